// Round 1
// 561.191 us; speedup vs baseline: 1.0240x; 1.0240x over previous
//
#include <hip/hip_runtime.h>
#include <cstdint>
#include <cstddef>

// Problem constants (fixed by the reference setup)
#define BS    2048
#define DIN   1024
#define DOUT  1024
#define SSEG  10
#define NPAR  30720          // dout * S * 3
#define NPK   20480          // packed smooth cols: S*DOUT*2 (ch1,ch2)
#define NCOL2 21504          // NPK + DOUT (norm appended)
#define NLG   10240          // S * DOUT logit columns (channel 0)
#define TAU   5e-5f          // near-boundary radius (~10x worst fp32-pipeline kp error)
#define WL_CAP 1048576u      // worklist capacity (entries)

// prep kernel regions
#define NB_SPLIT 2048        // x fp16x2 split blocks
#define NB_NORM  1024        // norm_W transpose blocks
#define NB_TRW   2560        // param_W transpose blocks (80 x 32)

// unified GEMM grid: 320 logit blocks (K=3072 via [xh|xl|xh]*[wh|wh|wlo]^T)
// + 672 smooth blocks (K=1024), 256x256 tiles, BK=32, 4-deep LDS ring.
#define GEMM_BLKS 992

typedef _Float16 half_t;
typedef __attribute__((ext_vector_type(8))) _Float16 half8;
typedef __attribute__((ext_vector_type(4))) _Float16 half4;
typedef __attribute__((ext_vector_type(2))) _Float16 half2v;
typedef __attribute__((ext_vector_type(4))) float   floatx4;

__device__ __forceinline__ void gload16(const void* g, void* l) {
  __builtin_amdgcn_global_load_lds(
      (const __attribute__((address_space(1))) void*)g,
      (__attribute__((address_space(3))) void*)l, 16, 0, 0);
}

// ---------------------------------------------------------------------------
__global__ void k_zero(unsigned* c) { if (threadIdx.x == 0) *c = 0; }

// ---------------------------------------------------------------------------
// Prep (3 regions):
//  [0, 2048):        x -> xh/xl fp16x2 split (+ zero worklist counter)
//  [2048, 3072):     norm_W transpose -> wsm rows [NPK, NCOL2)
//  [3072, 5632):     param_W 32k x 384col tiles ->
//                      wsm (ch1/ch2 fp16), wh/wlo (fp16x2 of 32w), wlt (fp32)
// ---------------------------------------------------------------------------
__global__ __launch_bounds__(256) void k_prep(const float* __restrict__ x,
                                              half_t* __restrict__ xh,
                                              half_t* __restrict__ xl,
                                              const float* __restrict__ nW,
                                              const float* __restrict__ pW,
                                              half_t* __restrict__ wsm,
                                              half_t* __restrict__ wh,
                                              half_t* __restrict__ wlo,
                                              float* __restrict__ wlt,
                                              unsigned* __restrict__ cnt) {
  __shared__ float tile[32][384];              // 48 KB (transw region)
  int bid = blockIdx.x;
  int tid = threadIdx.x;

  if (bid < NB_SPLIT) {
    if (bid == 0 && tid == 0) *cnt = 0;
    int i = bid * 256 + tid;                   // float4 groups over BS*DIN
    floatx4 v = ((const floatx4*)x)[i];
    half4 h, l;
    #pragma unroll
    for (int c = 0; c < 4; c++) { h[c] = (half_t)v[c]; l[c] = (half_t)(v[c] - (float)h[c]); }
    ((half4*)xh)[i] = h;
    ((half4*)xl)[i] = l;
    return;
  }

  if (bid < NB_SPLIT + NB_NORM) {
    int b2 = bid - NB_SPLIT;                   // 0..1023
    int col0 = (b2 & 31) * 32;
    int k0   = (b2 >> 5) * 32;
    int tx = tid & 31;
    int ty = tid >> 5;
    float* t33 = &tile[0][0];                  // reuse LDS as 32x33
    #pragma unroll
    for (int r = ty; r < 32; r += 8)
      t33[r * 33 + tx] = nW[(size_t)(k0 + r) * DOUT + col0 + tx];
    __syncthreads();
    #pragma unroll
    for (int r = ty; r < 32; r += 8)
      wsm[(size_t)(col0 + r + NPK) * DIN + k0 + tx] = (half_t)t33[tx * 33 + r];
    return;
  }

  // ---- transw region ----
  int b3 = bid - NB_SPLIT - NB_NORM;           // 0..2559
  int bx = b3 % 80;                            // 384-col group
  int k0 = (b3 / 80) * 32;                     // k tile
  int s  = bx >> 3;                            // logit segment
  int d0 = (bx & 7) * 128;

  const float* sb = pW + (size_t)k0 * NPAR + bx * 384;
  for (int i = tid; i < 32 * 96; i += 256) {   // 12 coalesced float4/thread
    int r = i / 96, q = i - r * 96;
    ((floatx4*)&tile[r][0])[q] = ((const floatx4*)(sb + (size_t)r * NPAR))[q];
  }
  __syncthreads();

  for (int ci = tid; ci < 3072; ci += 256) {
    if (ci < 1024) {                           // wsm ch1/ch2: 256 rows x 4 chunks
      int rl = ci >> 2, kc = ci & 3;
      int jj = rl >> 1, cbit = rl & 1;
      int col = 3 * jj + 1 + cbit;
      half8 v;
      #pragma unroll
      for (int m = 0; m < 8; m++) v[m] = (half_t)tile[kc * 8 + m][col];
      *(half8*)(wsm + (size_t)(s * 2048 + 2 * (d0 + jj) + cbit) * DIN + k0 + kc * 8) = v;
    } else if (ci < 1536) {                    // wh: 128 rows x 4 chunks
      int u = ci - 1024;
      int jj = u >> 2, kc = u & 3;
      half8 v;
      #pragma unroll
      for (int m = 0; m < 8; m++) v[m] = (half_t)(tile[kc * 8 + m][3 * jj] * 32.0f);
      *(half8*)(wh + (size_t)(s * 1024 + d0 + jj) * DIN + k0 + kc * 8) = v;
    } else if (ci < 2048) {                    // wlo: 128 rows x 4 chunks
      int u = ci - 1536;
      int jj = u >> 2, kc = u & 3;
      half8 v;
      #pragma unroll
      for (int m = 0; m < 8; m++) {
        float raw = tile[kc * 8 + m][3 * jj] * 32.0f;   // exact pow2 scale
        half_t h = (half_t)raw;
        v[m] = (half_t)(raw - (float)h);
      }
      *(half8*)(wlo + (size_t)(s * 1024 + d0 + jj) * DIN + k0 + kc * 8) = v;
    } else {                                   // wlt fp32: 128 rows x 8 chunks
      int u = ci - 2048;
      int jj = u >> 3, kc = u & 7;
      floatx4 v;
      #pragma unroll
      for (int m = 0; m < 4; m++) v[m] = tile[kc * 4 + m][3 * jj];
      *(floatx4*)(wlt + (size_t)(s * 1024 + d0 + jj) * DIN + k0 + kc * 4) = v;
    }
  }
}

// ---------------------------------------------------------------------------
// Unified deep-pipelined GEMM, 256x256 tile, BK=32, 512 threads (8 waves 2x4),
// per-wave 128x64 output. LDS: 4-deep ring for A and B (4x16KB each, 128 KiB).
// Stages issued 3 tiles ahead via global_load_lds; steady-state waits are
// vmcnt(8) (2 tiles of loads stay in flight across every barrier - never a
// drain in the main loop; epilogue drains 8->4->0).
//
// LDS layout (per 16KB tile buf): 128 lines x 128B; line L holds rows
// {2L, 2L+1} x 32 k-cols. 16B slot s of line L holds global chunk
// s ^ (L&7) (XOR swizzle): applied on BOTH the gload source address and the
// ds_read address -> A-frag reads spread uniformly over 8 slots (2 lanes per
// 16B slot = conflict-free).
//
// mode 0 (blocks 0..319):   Lg = ([xh|xl|xh] * [wh|wh|wlo]^T)/32 + bias, K=3072
// mode 1 (blocks 320..991): P  = xh * wsm^T + bias (fp16 out), K=1024
// ---------------------------------------------------------------------------
__global__ __launch_bounds__(512, 2) void k_gemm2(
    const half_t* __restrict__ xh, const half_t* __restrict__ xl,
    const half_t* __restrict__ wh, const half_t* __restrict__ wlo,
    const half_t* __restrict__ wsm,
    float* __restrict__ Lg, half_t* __restrict__ P,
    const float* __restrict__ pb, const float* __restrict__ nb) {
  __shared__ __attribute__((aligned(128))) char lds[131072];
  char* ldsA = lds;
  char* ldsB = lds + 65536;

  int bid = blockIdx.x;
  int tid = threadIdx.x;
  int w = tid >> 6, l = tid & 63;
  int wr = w >> 2, wc = w & 3;                 // wave grid 2 (rows) x 4 (cols)
  int l15 = l & 15, quad = l >> 4;

  int mode, mt, nt, KT;
  const half_t *A0, *A1, *A2, *B0, *B1, *B2;
  if (bid < 320) {                             // logit blocks first (3x work)
    int s = (bid & 7) * 40 + (bid >> 3);       // XCD-chunked (320 % 8 == 0)
    mode = 0; mt = s & 7; nt = s >> 3; KT = 96;
    A0 = xh; A1 = xl; A2 = xh; B0 = wh; B1 = wh; B2 = wlo;
  } else {
    int s2 = bid - 320;
    int s = (s2 & 7) * 84 + (s2 >> 3);         // 672 % 8 == 0
    mode = 1; mt = s & 7; nt = s >> 3; KT = 32;
    A0 = xh; A1 = xh; A2 = xh; B0 = wsm; B1 = wsm; B2 = wsm;
  }
  int m0 = mt * 256, n0 = nt * 256;

  // staging geometry: per (wave, instr j) -> 16 rows; lane l covers line
  // (l>>3), linear slot (l&7). Source chunk pre-swizzled: s' = (l&7)^(l>>3).
  int sp = (l & 7) ^ ((l >> 3) & 7);
  int srowA = m0 + w * 32 + 2 * (l >> 3) + (sp >> 2);
  int srowB = n0 + w * 32 + 2 * (l >> 3) + (sp >> 2);
  int scol = (sp & 3) * 8;

  // fragment read: row = base + l15 -> line base + (l15>>1), half l15&1,
  // chunk = quad; swizzled slot = ((l15&1)<<2 | quad) ^ (l15>>1).
  int lofs = (l15 >> 1) * 128 + (((((l15 & 1) << 2) | quad) ^ (l15 >> 1)) << 4);
  const char* pA = ldsA + wr * 8192 + lofs;    // + buf*16384 + m*4096 + mi*1024
  const char* pB = ldsB + wc * 4096 + lofs;    // + buf*16384 + ni*1024

  auto stA = [&](int kt) {                     // 2 gload16 (one 16KB A tile w/ all waves)
    const half_t* As = (kt < 32) ? A0 : ((kt < 64) ? A1 : A2);
    const half_t* g = As + (size_t)srowA * DIN + (kt & 31) * 32 + scol;
    char* lb = ldsA + (kt & 3) * 16384 + w * 2048;
    gload16(g, lb);
    gload16(g + 16 * DIN, lb + 1024);
  };
  auto stB = [&](int kt) {
    const half_t* Bs = (kt < 32) ? B0 : ((kt < 64) ? B1 : B2);
    const half_t* g = Bs + (size_t)srowB * DIN + (kt & 31) * 32 + scol;
    char* lb = ldsB + (kt & 3) * 16384 + w * 2048;
    gload16(g, lb);
    gload16(g + 16 * DIN, lb + 1024);
  };

  floatx4 acc[8][4] = {};

  // prologue: tiles 0,1,2 staged (12 loads); wait A0/B0 (keep 8 in flight)
  stA(0); stB(0); stA(1); stB(1); stA(2); stB(2);
  asm volatile("s_waitcnt vmcnt(8)" ::: "memory");
  __builtin_amdgcn_s_barrier();

  for (int kt = 0; kt < KT; ++kt) {
    const char* a = pA + (kt & 3) * 16384;
    const char* b = pB + (kt & 3) * 16384;
    half8 af[4], bf[4];
    // ---- phase 0: B frags (whole tile) + A frags rows [0,64) of wave half
    #pragma unroll
    for (int ni = 0; ni < 4; ni++) bf[ni] = *(const half8*)(b + ni * 1024);
    #pragma unroll
    for (int mi = 0; mi < 4; mi++) af[mi] = *(const half8*)(a + mi * 1024);
    if (kt + 3 < KT) stA(kt + 3);              // prefetch 3 tiles ahead
    __builtin_amdgcn_s_barrier();
    asm volatile("s_waitcnt lgkmcnt(0)" ::: "memory");
    __builtin_amdgcn_sched_barrier(0);
    __builtin_amdgcn_s_setprio(1);
    #pragma unroll
    for (int mi = 0; mi < 4; mi++)
      #pragma unroll
      for (int ni = 0; ni < 4; ni++)
        acc[mi][ni] = __builtin_amdgcn_mfma_f32_16x16x32_f16(af[mi], bf[ni], acc[mi][ni], 0, 0, 0);
    __builtin_amdgcn_s_setprio(0);
    __builtin_amdgcn_s_barrier();

    // ---- phase 1: A frags rows [64,128) of wave half (B kept in regs)
    #pragma unroll
    for (int mi = 0; mi < 4; mi++) af[mi] = *(const half8*)(a + 4096 + mi * 1024);
    if (kt + 3 < KT) stB(kt + 3);
    __builtin_amdgcn_s_barrier();
    asm volatile("s_waitcnt lgkmcnt(0)" ::: "memory");
    __builtin_amdgcn_sched_barrier(0);
    __builtin_amdgcn_s_setprio(1);
    #pragma unroll
    for (int mi = 0; mi < 4; mi++)
      #pragma unroll
      for (int ni = 0; ni < 4; ni++)
        acc[4 + mi][ni] = __builtin_amdgcn_mfma_f32_16x16x32_f16(af[mi], bf[ni], acc[4 + mi][ni], 0, 0, 0);
    __builtin_amdgcn_s_setprio(0);
    // counted wait: next tile's A/B done; 2 younger tiles stay in flight
    if (kt < KT - 3)       { asm volatile("s_waitcnt vmcnt(8)" ::: "memory"); }
    else if (kt == KT - 3) { asm volatile("s_waitcnt vmcnt(4)" ::: "memory"); }
    else if (kt == KT - 2) { asm volatile("s_waitcnt vmcnt(0)" ::: "memory"); }
    __builtin_amdgcn_s_barrier();
  }

  // ---- epilogue ----
  int rbase = m0 + wr * 128 + quad * 4;
  int cbase = n0 + wc * 64 + l15;
  if (mode == 0) {
    #pragma unroll
    for (int ni = 0; ni < 4; ni++) {
      int col = cbase + ni * 16;               // packed s*1024+d
      float bias = pb[(col >> 10) * 3072 + (col & 1023) * 3];
      #pragma unroll
      for (int mi = 0; mi < 8; mi++) {
        int row = rbase + mi * 16;
        floatx4 v = acc[mi][ni];
        #pragma unroll
        for (int r = 0; r < 4; r++)
          Lg[(size_t)(row + r) * NLG + col] = v[r] * 0.03125f + bias;
      }
    }
  } else {
    #pragma unroll
    for (int ni = 0; ni < 4; ni++) {
      int col = cbase + ni * 16;
      float bias;
      if (col < NPK) {
        int s = col >> 11, rem = col & 2047;
        bias = pb[s * 3072 + 3 * (rem >> 1) + 1 + (rem & 1)];
      } else {
        bias = nb[col - NPK];
      }
      #pragma unroll
      for (int mi = 0; mi < 8; mi++) {
        int row = rbase + mi * 16;
        floatx4 v = acc[mi][ni];
        #pragma unroll
        for (int r = 0; r < 4; r++)
          P[(size_t)(row + r) * NCOL2 + col] = (half_t)(v[r] + bias);
      }
    }
  }
}

// ---------------------------------------------------------------------------
// fp32 formula; mind = min_j |t - kp[j]| for near-boundary flagging
// ---------------------------------------------------------------------------
__device__ __forceinline__ float spiking_eval(const float* p, float tt, float* mind) {
  float mx = -1e30f;
  #pragma unroll
  for (int s = 0; s < SSEG; s++) mx = fmaxf(mx, p[3 * s]);
  float ew[10], wsum = 0.0f;
  #pragma unroll
  for (int s = 0; s < SSEG; s++) { ew[s] = __expf(p[3 * s] - mx); wsum += ew[s]; }
  float inv = 1.0f / wsum;

  float kp[11];
  kp[0] = -1.0f;
  float cum = 0.0f, md = 1e30f;
  #pragma unroll
  for (int s = 0; s < SSEG; s++) {
    cum += ew[s] * inv;
    kp[s + 1] = cum * 2.0f - 1.0f;
    md = fminf(md, fabsf(tt - kp[s + 1]));
  }
  *mind = md;

  float vf[10], resid[10];
  float lm = 0.0f, rm = 0.0f, integ = 0.0f;
  #pragma unroll
  for (int s = 0; s < SSEG; s++) {
    float p1 = p[3 * s + 1], p2 = p[3 * s + 2];
    float e2 = __expf(2.0f * fabsf(p1));
    float th = copysignf(1.0f - 2.0f / (e2 + 1.0f), p1);
    resid[s] = th * tt + p2;
    float st = kp[s], en = kp[s + 1];
    bool v = ((tt >= st) && (tt < en)) || ((tt == 1.0f) && (en == 1.0f));
    float vv = v ? 1.0f : 0.0f;
    vf[s] = vv;
    lm += (tt - st) * vv;
    rm += (en - tt) * vv;
    integ += 0.5f * th * (en * en - st * st) + p2 * (ew[s] * inv);
  }
  float resLV = 0.0f, resV = 0.0f, resRV = 0.0f;
  #pragma unroll
  for (int s = 0; s < SSEG; s++) {
    float lv = (s == 0) ? vf[0] : vf[s - 1];
    float rv = (s == 9) ? vf[9] : vf[s + 1];
    resLV += resid[s] * lv;
    resV  += resid[s] * vf[s];
    resRV += resid[s] * rv;
  }
  float lw = 1.0f / (1.0f + __expf(50.0f * lm));
  float rw = 1.0f / (1.0f + __expf(50.0f * rm));
  float swt = 1.0f - lw - rw;
  return lw * resLV + swt * resV + rw * resRV - 0.5f * integ + p[30];
}

// ---------------------------------------------------------------------------
// Pointwise: logits fp32 from Lg, ch1/2+norm fp16 from P. Flags near-boundary.
// ---------------------------------------------------------------------------
__global__ __launch_bounds__(256) void k_pointwise(const half_t* __restrict__ P,
                                                   const float* __restrict__ Lg,
                                                   const float* __restrict__ t,
                                                   float* __restrict__ out,
                                                   unsigned* __restrict__ cnt,
                                                   unsigned* __restrict__ wl,
                                                   unsigned cap) {
  __shared__ __attribute__((aligned(16))) half_t sp[SSEG * 512];
  int b = blockIdx.x, dg = blockIdx.y, tid = threadIdx.x;
  const half_t* Pb = P + (size_t)b * NCOL2;
  for (int i = tid; i < SSEG * 64; i += 256) {     // 640 x 16B
    int s = i >> 6, e = i & 63;
    ((uint4*)sp)[(s << 6) + e] = ((const uint4*)(Pb + s * 2048 + dg * 512))[e];
  }
  float tt = t[b];
  float nt = (float)Pb[NPK + dg * 256 + tid];
  const float* Lb = Lg + (size_t)b * NLG + dg * 256 + tid;
  __syncthreads();

  float p[31];
  #pragma unroll
  for (int s = 0; s < SSEG; s++) {
    p[3 * s] = Lb[s * 1024];                       // accurate logit (bias incl.)
    half2v hv = ((const half2v*)sp)[s * 256 + tid];  // 4B/lane, conflict-free
    p[3 * s + 1] = (float)hv.x;
    p[3 * s + 2] = (float)hv.y;
  }
  p[30] = nt;
  float mind;
  float r = spiking_eval(p, tt, &mind);
  int d = dg * 256 + tid;
  out[(size_t)b * DOUT + d] = r;
  if (wl != nullptr && mind < TAU) {
    unsigned idx = atomicAdd(cnt, 1u);
    if (idx < cap) wl[idx] = ((unsigned)b << 10) | (unsigned)d;
  }
}

// ---------------------------------------------------------------------------
// Fallback: fused naive fp32 + flagging (tiny-workspace insurance)
// ---------------------------------------------------------------------------
__global__ __launch_bounds__(256) void k_naive(const float* __restrict__ x,
                                               const float* __restrict__ t,
                                               const float* __restrict__ pW,
                                               const float* __restrict__ pb,
                                               const float* __restrict__ nW,
                                               const float* __restrict__ nb,
                                               float* __restrict__ out,
                                               unsigned* __restrict__ cnt,
                                               unsigned* __restrict__ wl,
                                               unsigned cap) {
  __shared__ float xs[DIN];
  int b = blockIdx.x, dg = blockIdx.y, tid = threadIdx.x;
  for (int i = tid; i < DIN; i += 256) xs[i] = x[(size_t)b * DIN + i];
  __syncthreads();
  int d = dg * 256 + tid;
  float acc[31];
  #pragma unroll
  for (int i = 0; i < 31; i++) acc[i] = 0.0f;
  for (int k = 0; k < DIN; k++) {
    float xv = xs[k];
    const float* wr = pW + (size_t)k * NPAR + 3 * d;
    #pragma unroll
    for (int s = 0; s < SSEG; s++) {
      acc[3 * s]     += xv * wr[s * 3072];
      acc[3 * s + 1] += xv * wr[s * 3072 + 1];
      acc[3 * s + 2] += xv * wr[s * 3072 + 2];
    }
    acc[30] += xv * nW[(size_t)k * DOUT + d];
  }
  #pragma unroll
  for (int s = 0; s < SSEG; s++) {
    acc[3 * s]     += pb[s * 3072 + 3 * d];
    acc[3 * s + 1] += pb[s * 3072 + 3 * d + 1];
    acc[3 * s + 2] += pb[s * 3072 + 3 * d + 2];
  }
  acc[30] += nb[d];
  float mind;
  float r = spiking_eval(acc, t[b], &mind);
  out[(size_t)b * DOUT + d] = r;
  if (wl != nullptr && mind < TAU) {
    unsigned idx = atomicAdd(cnt, 1u);
    if (idx < cap) wl[idx] = ((unsigned)b << 10) | (unsigned)d;
  }
}

// ---------------------------------------------------------------------------
// f64 redo: one wave per flagged (b,d). haveP: coalesced WLt logit weights +
// fp16 smooth channels from P. !haveP: pW gather (fallback path).
// ---------------------------------------------------------------------------
__global__ __launch_bounds__(256) void k_redo(const float* __restrict__ x,
                                              const float* __restrict__ t,
                                              const float* __restrict__ pW,
                                              const float* __restrict__ pb,
                                              const float* __restrict__ nW,
                                              const float* __restrict__ nb,
                                              const half_t* __restrict__ P,
                                              const float* __restrict__ WLt,
                                              int haveP,
                                              const unsigned* __restrict__ cnt,
                                              const unsigned* __restrict__ wl,
                                              unsigned cap,
                                              float* __restrict__ out) {
  unsigned n = *cnt;
  if (n > cap) n = cap;
  int lane = threadIdx.x & 63;
  unsigned wave = (blockIdx.x * 256 + threadIdx.x) >> 6;
  unsigned nwaves = (gridDim.x * 256) >> 6;

  for (unsigned e = wave; e < n; e += nwaves) {
    unsigned code = wl[e];
    int b = (int)(code >> 10), d = (int)(code & 1023);

    double lg[10], sl[10], ic[10], nt = 0.0;
    #pragma unroll
    for (int s = 0; s < SSEG; s++) { lg[s] = 0.0; sl[s] = 0.0; ic[s] = 0.0; }

    if (haveP) {
      for (int k = lane; k < DIN; k += 64) {     // coalesced WLt rows
        double xv = (double)x[(size_t)b * DIN + k];
        #pragma unroll
        for (int s = 0; s < SSEG; s++)
          lg[s] += xv * (double)WLt[(size_t)(s * 1024 + d) * DIN + k];
      }
    } else {
      for (int k = lane; k < DIN; k += 64) {
        double xv = (double)x[(size_t)b * DIN + k];
        const float* wr = pW + (size_t)k * NPAR + 3 * d;
        #pragma unroll
        for (int s = 0; s < SSEG; s++) {
          lg[s] += xv * (double)wr[s * 3072];
          sl[s] += xv * (double)wr[s * 3072 + 1];
          ic[s] += xv * (double)wr[s * 3072 + 2];
        }
        nt += xv * (double)nW[(size_t)k * DOUT + d];
      }
    }
    #pragma unroll
    for (int off = 32; off > 0; off >>= 1) {
      #pragma unroll
      for (int s = 0; s < SSEG; s++) lg[s] += __shfl_down(lg[s], off);
      if (!haveP) {
        #pragma unroll
        for (int s = 0; s < SSEG; s++) {
          sl[s] += __shfl_down(sl[s], off);
          ic[s] += __shfl_down(ic[s], off);
        }
        nt += __shfl_down(nt, off);
      }
    }

    if (lane == 0) {
      double slope[10], icpt[10], ntv;
      if (haveP) {
        const half_t* Pr = P + (size_t)b * NCOL2;
        #pragma unroll
        for (int s = 0; s < SSEG; s++) {
          slope[s] = tanh((double)(float)Pr[s * 2048 + 2 * d]);
          icpt[s]  = (double)(float)Pr[s * 2048 + 2 * d + 1];
        }
        ntv = (double)(float)Pr[NPK + d];
      } else {
        #pragma unroll
        for (int s = 0; s < SSEG; s++) {
          slope[s] = tanh(sl[s] + (double)pb[s * 3072 + 3 * d + 1]);
          icpt[s]  = ic[s] + (double)pb[s * 3072 + 3 * d + 2];
        }
        ntv = nt + (double)nb[d];
      }
      #pragma unroll
      for (int s = 0; s < SSEG; s++) lg[s] += (double)pb[s * 3072 + 3 * d];

      double mx = -1e300;
      #pragma unroll
      for (int s = 0; s < SSEG; s++) mx = fmax(mx, lg[s]);
      double ew[10], ws = 0.0;
      #pragma unroll
      for (int s = 0; s < SSEG; s++) { ew[s] = exp(lg[s] - mx); ws += ew[s]; }

      double kp[11];
      kp[0] = -1.0;
      double cum = 0.0;
      #pragma unroll
      for (int s = 0; s < SSEG; s++) { cum += ew[s] / ws; kp[s + 1] = cum * 2.0 - 1.0; }

      double tt = (double)t[b];
      double vf[10], resid[10], lm = 0.0, rm = 0.0, integ = 0.0;
      #pragma unroll
      for (int s = 0; s < SSEG; s++) {
        double st = kp[s], en = kp[s + 1];
        bool v = ((tt >= st) && (tt < en)) || ((tt == 1.0) && (en == 1.0));
        double vv = v ? 1.0 : 0.0;
        vf[s] = vv;
        resid[s] = slope[s] * tt + icpt[s];
        lm += (tt - st) * vv;
        rm += (en - tt) * vv;
        integ += 0.5 * slope[s] * (en * en - st * st) + icpt[s] * (ew[s] / ws);
      }
      double rLV = 0.0, rV = 0.0, rRV = 0.0;
      #pragma unroll
      for (int s = 0; s < SSEG; s++) {
        double lv = (s == 0) ? vf[0] : vf[s - 1];
        double rv = (s == 9) ? vf[9] : vf[s + 1];
        rLV += resid[s] * lv;
        rV  += resid[s] * vf[s];
        rRV += resid[s] * rv;
      }
      double lw = 1.0 / (1.0 + exp(50.0 * lm));
      double rw = 1.0 / (1.0 + exp(50.0 * rm));
      double res = lw * rLV + (1.0 - lw - rw) * rV + rw * rRV - 0.5 * integ + ntv;
      out[(size_t)b * DOUT + d] = (float)res;
    }
  }
}

// ---------------------------------------------------------------------------
extern "C" void kernel_launch(void* const* d_in, const int* in_sizes, int n_in,
                              void* d_out, int out_size, void* d_ws, size_t ws_size,
                              hipStream_t stream) {
  const float* x  = (const float*)d_in[0];
  const float* t  = (const float*)d_in[1];
  const float* pW = (const float*)d_in[2];
  const float* pb = (const float*)d_in[3];
  const float* nW = (const float*)d_in[4];
  const float* nb = (const float*)d_in[5];
  float* out = (float*)d_out;

  // workspace layout (counter+worklist first so the fallback works with tiny ws)
  const size_t o_cnt = 0;
  const size_t o_wl  = 64;
  const size_t o_xh  = o_wl  + (size_t)WL_CAP * 4;         //  4 MiB
  const size_t o_xl  = o_xh  + (size_t)BS * DIN * 2;       //  4 MiB
  const size_t o_wsm = o_xl  + (size_t)BS * DIN * 2;       // 44 MiB (NCOL2 fp16)
  const size_t o_wh  = o_wsm + (size_t)NCOL2 * DIN * 2;    // 20 MiB
  const size_t o_wlo = o_wh  + (size_t)NLG * DIN * 2;      // 20 MiB
  const size_t o_wlt = o_wlo + (size_t)NLG * DIN * 2;      // 40 MiB (fp32 logit W^T)
  const size_t o_p   = o_wlt + (size_t)NLG * DIN * 4;      // 88 MiB (fp16 P2)
  const size_t o_lg  = o_p   + (size_t)BS * NCOL2 * 2;     // 84 MiB
  const size_t need  = o_lg  + (size_t)BS * NLG * 4;       // ~308 MiB total

  bool have_wl = ws_size >= 1024 * 1024;
  unsigned* cnt = (unsigned*)((char*)d_ws + o_cnt);
  unsigned* wl  = (unsigned*)((char*)d_ws + o_wl);
  unsigned cap  = 0;
  if (have_wl) {
    size_t avail = (ws_size >= need) ? (size_t)WL_CAP
                                     : (ws_size - o_wl) / 4;
    cap = (unsigned)(avail < WL_CAP ? avail : WL_CAP);
  }

  if (ws_size >= need) {
    half_t* xh  = (half_t*)((char*)d_ws + o_xh);
    half_t* xl  = (half_t*)((char*)d_ws + o_xl);
    half_t* wsm = (half_t*)((char*)d_ws + o_wsm);
    half_t* wh  = (half_t*)((char*)d_ws + o_wh);
    half_t* wlo = (half_t*)((char*)d_ws + o_wlo);
    float*  wlt = (float*)((char*)d_ws + o_wlt);
    half_t* P   = (half_t*)((char*)d_ws + o_p);
    float*  Lg  = (float*)((char*)d_ws + o_lg);

    k_prep<<<NB_SPLIT + NB_NORM + NB_TRW, 256, 0, stream>>>(x, xh, xl, nW, pW,
                                                            wsm, wh, wlo, wlt, cnt);
    k_gemm2<<<GEMM_BLKS, 512, 0, stream>>>(xh, xl, wh, wlo, wsm, Lg, P, pb, nb);
    k_pointwise<<<dim3(BS, DOUT / 256), 256, 0, stream>>>(P, Lg, t, out, cnt,
                                                          have_wl ? wl : nullptr, cap);
    if (have_wl)
      k_redo<<<256, 256, 0, stream>>>(x, t, pW, pb, nW, nb, P, wlt, 1, cnt, wl, cap, out);
  } else {
    if (have_wl) k_zero<<<1, 64, 0, stream>>>(cnt);
    k_naive<<<dim3(BS, DOUT / 256), 256, 0, stream>>>(x, t, pW, pb, nW, nb, out, cnt,
                                                      have_wl ? wl : nullptr, cap);
    if (have_wl)
      k_redo<<<256, 256, 0, stream>>>(x, t, pW, pb, nW, nb, nullptr, nullptr, 0,
                                      cnt, wl, cap, out);
  }
}